// Round 1
// baseline (572.429 us; speedup 1.0000x reference)
//
#include <hip/hip_runtime.h>

#define N 1024
#define T 32
#define GH (T + 8)   // gray extent  (halo 4)
#define BH (T + 4)   // blurred extent (halo 2)
#define MH (T + 2)   // magnitude extent (halo 1)

// reflect-101 (jnp.pad mode='reflect'), valid for |overshoot| <= 4
__device__ __forceinline__ int refl(int i) {
    if (i < 0) return -i;
    if (i >= N) return 2 * N - 2 - i;
    return i;
}

__device__ __forceinline__ int clampi(int i) {
    return i < 0 ? 0 : (i > N - 1 ? N - 1 : i);
}

struct Smem {
    float G[GH][GH];
    float B[BH][BH];
    float M[MH][MH];
};

// Computes the binary edge map for one image tile; returns 4 edge bits
// (one per center pixel handled by this thread).
__device__ unsigned int edge_pass(const float* __restrict__ img, int r0, int c0,
                                  Smem& s, int tid)
{
    // gaussian_kernel_2d(5, 1.0), normalized (outer product of wv)
    const float wv[5] = {0.05448868f, 0.24420134f, 0.40261996f, 0.24420134f, 0.05448868f};

    // Stage A: gray (RGB dot) with reflect-101 indices, into LDS
    for (int p = tid; p < GH * GH; p += 256) {
        int i = p / GH, j = p % GH;
        int rr = refl(r0 - 4 + i);
        int cc = refl(c0 - 4 + j);
        size_t o = (size_t)rr * N + cc;
        float g = 0.299f * img[o]
                + 0.587f * img[o + (size_t)N * N]
                + 0.114f * img[o + 2 * (size_t)N * N];
        s.G[i][j] = g;
    }
    __syncthreads();

    // Stage B: 5x5 Gaussian blur (only for in-image positions; OOB never read)
    for (int p = tid; p < BH * BH; p += 256) {
        int i = p / BH, j = p % BH;
        int gr = r0 - 2 + i, gc = c0 - 2 + j;
        if (gr >= 0 && gr < N && gc >= 0 && gc < N) {
            float acc = 0.f;
#pragma unroll
            for (int a = 0; a < 5; ++a) {
                float h = 0.f;
#pragma unroll
                for (int b2 = 0; b2 < 5; ++b2)
                    h += wv[b2] * s.G[i + a][j + b2];
                acc += wv[a] * h;
            }
            s.B[i][j] = acc;
        }
    }
    __syncthreads();

    // Stage C: Sobel magnitude (edge-clamped reads of B); zero outside image
    for (int p = tid; p < MH * MH; p += 256) {
        int i = p / MH, j = p % MH;
        int gr = r0 - 1 + i, gc = c0 - 1 + j;
        float m = 0.f;
        if (gr >= 0 && gr < N && gc >= 0 && gc < N) {
            int rm = clampi(gr - 1) - (r0 - 2), rc = gr - (r0 - 2), rp = clampi(gr + 1) - (r0 - 2);
            int cm = clampi(gc - 1) - (c0 - 2), cc = gc - (c0 - 2), cp = clampi(gc + 1) - (c0 - 2);
            float a00 = s.B[rm][cm], a01 = s.B[rm][cc], a02 = s.B[rm][cp];
            float a10 = s.B[rc][cm],                    a12 = s.B[rc][cp];
            float a20 = s.B[rp][cm], a21 = s.B[rp][cc], a22 = s.B[rp][cp];
            float gx = (a02 - a00) + 2.f * (a12 - a10) + (a22 - a20);
            float gy = (a20 - a00) + 2.f * (a21 - a01) + (a22 - a02);
            m = sqrtf(gx * gx + gy * gy + 1e-6f);
        }
        s.M[i][j] = m;
    }
    __syncthreads();

    // Stage D: NMS axis via tan comparisons (replaces atan2/round/mod) + threshold
    unsigned int bits = 0;
    const float T1 = 0.41421356f;  // tan 22.5
    const float T2 = 2.41421356f;  // tan 67.5
#pragma unroll
    for (int k = 0; k < (T * T) / 256; ++k) {
        int p = tid + k * 256;
        int pr = p >> 5, pc = p & 31;  // T == 32
        int gr = r0 + pr, gc = c0 + pc;
        // recompute Sobel at the center for the direction decision
        int rm = clampi(gr - 1) - (r0 - 2), rc = gr - (r0 - 2), rp = clampi(gr + 1) - (r0 - 2);
        int cm = clampi(gc - 1) - (c0 - 2), cc = gc - (c0 - 2), cp = clampi(gc + 1) - (c0 - 2);
        float a00 = s.B[rm][cm], a01 = s.B[rm][cc], a02 = s.B[rm][cp];
        float a10 = s.B[rc][cm],                    a12 = s.B[rc][cp];
        float a20 = s.B[rp][cm], a21 = s.B[rp][cc], a22 = s.B[rp][cp];
        float gx = (a02 - a00) + 2.f * (a12 - a10) + (a22 - a20);
        float gy = (a20 - a00) + 2.f * (a21 - a01) + (a22 - a02);
        float ax = fabsf(gx), ay = fabsf(gy);
        int dr1, dc1;
        if (ay <= T1 * ax)      { dr1 = 0;  dc1 = 1; }   // E/W pair (idx 0/4)
        else if (ay >= T2 * ax) { dr1 = -1; dc1 = 0; }   // N/S pair (idx 2/6)
        else if ((gx > 0.f) == (gy > 0.f)) { dr1 = -1; dc1 = 1; }  // NE/SW (1/5)
        else                    { dr1 = -1; dc1 = -1; }  // NW/SE (3/7)
        float m = s.M[pr + 1][pc + 1];
        int r1 = gr + dr1, c1 = gc + dc1;
        int r2 = gr - dr1, c2 = gc - dc1;
        float n1 = (r1 >= 0 && r1 < N && c1 >= 0 && c1 < N) ? s.M[pr + 1 + dr1][pc + 1 + dc1] : 0.f;
        float n2 = (r2 >= 0 && r2 < N && c2 >= 0 && c2 < N) ? s.M[pr + 1 - dr1][pc + 1 - dc1] : 0.f;
        bool edge = (m - n1 > 0.f) && (m - n2 > 0.f) && (m > 0.1f);
        bits |= (unsigned)edge << k;
    }
    return bits;
}

__global__ __launch_bounds__(256)
void edge_diff_kernel(const float* __restrict__ op, const float* __restrict__ gt,
                      unsigned int* __restrict__ cnt)
{
    __shared__ Smem s;
    int tid = threadIdx.x;
    int b = blockIdx.z;
    int r0 = blockIdx.y * T, c0 = blockIdx.x * T;
    const float* imgA = op + (size_t)b * 3 * N * N;
    const float* imgB = gt + (size_t)b * 3 * N * N;

    unsigned int e1 = edge_pass(imgA, r0, c0, s, tid);
    __syncthreads();  // barrier between passes (D reads vs next A/B writes)
    unsigned int e2 = edge_pass(imgB, r0, c0, s, tid);

    int d = __popc(e1 ^ e2);
    // wave-64 reduction
    for (int off = 32; off > 0; off >>= 1)
        d += __shfl_down(d, off, 64);
    if ((tid & 63) == 0)
        atomicAdd(cnt, (unsigned int)d);
}

__global__ void finalize_kernel(const unsigned int* __restrict__ cnt, float* __restrict__ out)
{
    out[0] = (float)cnt[0] / 8388608.0f;  // 8 * 1024 * 1024
}

extern "C" void kernel_launch(void* const* d_in, const int* in_sizes, int n_in,
                              void* d_out, int out_size, void* d_ws, size_t ws_size,
                              hipStream_t stream)
{
    const float* op = (const float*)d_in[0];
    const float* gt = (const float*)d_in[1];
    unsigned int* cnt = (unsigned int*)d_ws;

    hipMemsetAsync(cnt, 0, sizeof(unsigned int), stream);
    dim3 grid(N / T, N / T, 8);
    edge_diff_kernel<<<grid, dim3(256), 0, stream>>>(op, gt, cnt);
    finalize_kernel<<<1, 1, 0, stream>>>(cnt, (float*)d_out);
}

// Round 2
// 542.433 us; speedup vs baseline: 1.0553x; 1.0553x over previous
//
#include <hip/hip_runtime.h>

#define N 1024
#define T 32
#define P 44            // LDS row pitch (floats); multiple of 4, 12 mod 32 banks

__device__ __forceinline__ int refl(int i) {      // reflect-101, |overshoot|<=4
    if (i < 0) return -i;
    if (i >= N) return 2 * N - 2 - i;
    return i;
}
__device__ __forceinline__ int clampi(int i) {
    return i < 0 ? 0 : (i > N - 1 ? N - 1 : i);
}
__device__ __forceinline__ int axis_code(float gx, float gy) {
    float ax = fabsf(gx), ay = fabsf(gy);
    if (ay <= 0.41421356f * ax) return 0;          // E/W
    if (ay >= 2.41421356f * ax) return 1;          // N/S
    return ((gx > 0.f) == (gy > 0.f)) ? 2 : 3;     // NE/SW : NW/SE
}

struct Smem {
    float S0[40 * P];            // G (gray, 40x40), later B (blur, 36x36)
    float S1[40 * P];            // H (hblur, 40x36), later M (mag, 34x36)
    unsigned char axis[32 * 33];
};

__device__ unsigned int edge_pass(const float* __restrict__ img, int r0, int c0,
                                  Smem& s, int tid)
{
    const float w0 = 0.05448868f, w1 = 0.24420134f, w2 = 0.40261996f,
                w3 = 0.24420134f, w4 = 0.05448868f;
    const bool colInterior = (c0 >= 32 && c0 <= 960);

    // ---- Stage A: gray into G (rows r0-4.., cols c0-4..c0+35) ----
    if (colInterior) {
        for (int t = tid; t < 400; t += 256) {     // 40 rows x 10 float4-groups
            int i = t / 10, q = t % 10;
            int rr = refl(r0 - 4 + i);
            const float4* pch = (const float4*)(img + (size_t)rr * N + (c0 - 4 + 4 * q));
            float4 r = pch[0];
            float4 g = pch[N * N / 4];
            float4 b = pch[2 * (N * N / 4)];
            float4 gy4;
            gy4.x = 0.299f * r.x + 0.587f * g.x + 0.114f * b.x;
            gy4.y = 0.299f * r.y + 0.587f * g.y + 0.114f * b.y;
            gy4.z = 0.299f * r.z + 0.587f * g.z + 0.114f * b.z;
            gy4.w = 0.299f * r.w + 0.587f * g.w + 0.114f * b.w;
            *(float4*)&s.S0[i * P + 4 * q] = gy4;
        }
    } else {
        for (int t = tid; t < 1600; t += 256) {
            int i = t / 40, j = t % 40;
            int rr = refl(r0 - 4 + i);
            int cc = refl(c0 - 4 + j);
            size_t o = (size_t)rr * N + cc;
            s.S0[i * P + j] = 0.299f * img[o] + 0.587f * img[o + (size_t)N * N]
                            + 0.114f * img[o + 2 * (size_t)N * N];
        }
    }
    __syncthreads();

    // ---- Stage B-h: horizontal blur G->H. H col j <-> gc = c0-2+j, j=0..35 ----
    for (int t = tid; t < 360; t += 256) {         // 40 rows x 9 groups
        int i = t / 9, q = t % 9;
        const float* gp = &s.S0[i * P + 4 * q];
        float4 g0 = *(const float4*)gp;
        float4 g1 = *(const float4*)(gp + 4);
        float4 h;
        h.x = w0 * g0.x + w1 * g0.y + w2 * g0.z + w3 * g0.w + w4 * g1.x;
        h.y = w0 * g0.y + w1 * g0.z + w2 * g0.w + w3 * g1.x + w4 * g1.y;
        h.z = w0 * g0.z + w1 * g0.w + w2 * g1.x + w3 * g1.y + w4 * g1.z;
        h.w = w0 * g0.w + w1 * g1.x + w2 * g1.y + w3 * g1.z + w4 * g1.w;
        *(float4*)&s.S1[i * P + 4 * q] = h;
    }
    __syncthreads();

    // ---- Stage B-v: vertical blur H->B. B row i <-> gr = r0-2+i, i=0..35 ----
    for (int t = tid; t < 324; t += 256) {         // 36 rows x 9 groups
        int i = t / 9, q = t % 9;
        const float* hp = &s.S1[i * P + 4 * q];
        float4 h0 = *(const float4*)hp;
        float4 h1 = *(const float4*)(hp + P);
        float4 h2 = *(const float4*)(hp + 2 * P);
        float4 h3 = *(const float4*)(hp + 3 * P);
        float4 h4 = *(const float4*)(hp + 4 * P);
        float4 b;
        b.x = w0 * h0.x + w1 * h1.x + w2 * h2.x + w3 * h3.x + w4 * h4.x;
        b.y = w0 * h0.y + w1 * h1.y + w2 * h2.y + w3 * h3.y + w4 * h4.y;
        b.z = w0 * h0.z + w1 * h1.z + w2 * h2.z + w3 * h3.z + w4 * h4.z;
        b.w = w0 * h0.w + w1 * h1.w + w2 * h2.w + w3 * h3.w + w4 * h4.w;
        *(float4*)&s.S0[i * P + 4 * q] = b;
    }
    __syncthreads();

    // ---- Stage C: Sobel magnitude B->M (+axis for centers) ----
    // M row i <-> gr = r0-1+i (i=0..33); M col j <-> gc = c0-1+j
    if (colInterior) {
        for (int t = tid; t < 306; t += 256) {     // 34 rows x 9 groups
            int i = t / 9, q = t % 9;
            int gr = r0 - 1 + i;
            int rci = i + 1;
            int rmi = (gr - 1 < 0 ? 0 : gr - 1) - (r0 - 2);
            int rpi = (gr + 1 > N - 1 ? N - 1 : gr + 1) - (r0 - 2);
            const float* bp = &s.S0[4 * q];
            float4 t0 = *(const float4*)(bp + rmi * P);
            float4 t1 = *(const float4*)(bp + rmi * P + 4);
            float4 m0 = *(const float4*)(bp + rci * P);
            float4 m1 = *(const float4*)(bp + rci * P + 4);
            float4 b0 = *(const float4*)(bp + rpi * P);
            float4 b1 = *(const float4*)(bp + rpi * P + 4);
            float tr[6] = {t0.x, t0.y, t0.z, t0.w, t1.x, t1.y};
            float mr[6] = {m0.x, m0.y, m0.z, m0.w, m1.x, m1.y};
            float br[6] = {b0.x, b0.y, b0.z, b0.w, b1.x, b1.y};
            float4 mag;
            float mk[4];
#pragma unroll
            for (int k = 0; k < 4; ++k) {
                float gx = (tr[k + 2] - tr[k]) + 2.f * (mr[k + 2] - mr[k]) + (br[k + 2] - br[k]);
                float gyv = (br[k] - tr[k]) + 2.f * (br[k + 1] - tr[k + 1]) + (br[k + 2] - tr[k + 2]);
                mk[k] = sqrtf(gx * gx + gyv * gyv + 1e-6f);
                int jj = 4 * q + k;
                if (i >= 1 && i <= 32 && jj >= 1 && jj <= 32)
                    s.axis[(i - 1) * 33 + (jj - 1)] = (unsigned char)axis_code(gx, gyv);
            }
            mag.x = mk[0]; mag.y = mk[1]; mag.z = mk[2]; mag.w = mk[3];
            *(float4*)&s.S1[i * P + 4 * q] = mag;
        }
    } else {
        for (int p = tid; p < 34 * 34; p += 256) {
            int i = p / 34, j = p % 34;
            int gr = r0 - 1 + i, gc = c0 - 1 + j;
            float m = 0.f;
            if (gr >= 0 && gr < N && gc >= 0 && gc < N) {
                int rm = clampi(gr - 1) - (r0 - 2), rc = gr - (r0 - 2), rp = clampi(gr + 1) - (r0 - 2);
                int cm = clampi(gc - 1) - (c0 - 2), cc = gc - (c0 - 2), cp = clampi(gc + 1) - (c0 - 2);
                float a00 = s.S0[rm * P + cm], a01 = s.S0[rm * P + cc], a02 = s.S0[rm * P + cp];
                float a10 = s.S0[rc * P + cm],                          a12 = s.S0[rc * P + cp];
                float a20 = s.S0[rp * P + cm], a21 = s.S0[rp * P + cc], a22 = s.S0[rp * P + cp];
                float gx = (a02 - a00) + 2.f * (a12 - a10) + (a22 - a20);
                float gyv = (a20 - a00) + 2.f * (a21 - a01) + (a22 - a02);
                m = sqrtf(gx * gx + gyv * gyv + 1e-6f);
                if (i >= 1 && i <= 32 && j >= 1 && j <= 32)
                    s.axis[(i - 1) * 33 + (j - 1)] = (unsigned char)axis_code(gx, gyv);
            }
            s.S1[i * P + j] = m;
        }
    }
    __syncthreads();

    // ---- Stage D: NMS + threshold -> 4 edge bits per thread ----
    unsigned int bits = 0;
#pragma unroll
    for (int k = 0; k < 4; ++k) {
        int p = tid + 256 * k;
        int pr = p >> 5, pc = p & 31;
        float m = s.S1[(pr + 1) * P + (pc + 1)];
        int code = s.axis[pr * 33 + pc];
        int dr = (code == 0) ? 0 : -1;
        int dc = (code == 1) ? 0 : ((code == 3) ? -1 : 1);
        int gr = r0 + pr, gc = c0 + pc;
        int r1 = gr + dr, c1 = gc + dc;
        int r2 = gr - dr, c2 = gc - dc;
        float n1 = (r1 >= 0 && r1 < N && c1 >= 0 && c1 < N)
                     ? s.S1[(pr + 1 + dr) * P + (pc + 1 + dc)] : 0.f;
        float n2 = (r2 >= 0 && r2 < N && c2 >= 0 && c2 < N)
                     ? s.S1[(pr + 1 - dr) * P + (pc + 1 - dc)] : 0.f;
        bool edge = (m - n1 > 0.f) && (m - n2 > 0.f) && (m > 0.1f);
        bits |= (unsigned)edge << k;
    }
    return bits;
}

__global__ __launch_bounds__(256)
void edge_diff_kernel(const float* __restrict__ op, const float* __restrict__ gt,
                      unsigned int* __restrict__ cnt)
{
    __shared__ Smem s;
    int tid = threadIdx.x;
    int b = blockIdx.z;
    int r0 = blockIdx.y * T, c0 = blockIdx.x * T;
    const float* imgA = op + (size_t)b * 3 * N * N;
    const float* imgB = gt + (size_t)b * 3 * N * N;

    unsigned int e1 = edge_pass(imgA, r0, c0, s, tid);
    __syncthreads();
    unsigned int e2 = edge_pass(imgB, r0, c0, s, tid);

    int d = __popc(e1 ^ e2);
    for (int off = 32; off > 0; off >>= 1)
        d += __shfl_down(d, off, 64);
    if ((tid & 63) == 0)
        atomicAdd(cnt, (unsigned int)d);
}

__global__ void finalize_kernel(const unsigned int* __restrict__ cnt, float* __restrict__ out)
{
    out[0] = (float)cnt[0] / 8388608.0f;   // 8 * 1024 * 1024
}

extern "C" void kernel_launch(void* const* d_in, const int* in_sizes, int n_in,
                              void* d_out, int out_size, void* d_ws, size_t ws_size,
                              hipStream_t stream)
{
    const float* op = (const float*)d_in[0];
    const float* gt = (const float*)d_in[1];
    unsigned int* cnt = (unsigned int*)d_ws;

    hipMemsetAsync(cnt, 0, sizeof(unsigned int), stream);
    dim3 grid(N / T, N / T, 8);
    edge_diff_kernel<<<grid, dim3(256), 0, stream>>>(op, gt, cnt);
    finalize_kernel<<<1, 1, 0, stream>>>(cnt, (float*)d_out);
}

// Round 3
// 245.481 us; speedup vs baseline: 2.3319x; 2.2097x over previous
//
#include <hip/hip_runtime.h>

#define N 1024
#define T 32
#define P 44            // LDS row pitch (floats); multiple of 4, 12 mod 32 banks
#define NBLK (32 * 32 * 8)

__device__ __forceinline__ int refl(int i) {      // reflect-101, |overshoot|<=4
    if (i < 0) return -i;
    if (i >= N) return 2 * N - 2 - i;
    return i;
}
__device__ __forceinline__ int clampi(int i) {
    return i < 0 ? 0 : (i > N - 1 ? N - 1 : i);
}
__device__ __forceinline__ int axis_code(float gx, float gy) {
    float ax = fabsf(gx), ay = fabsf(gy);
    if (ay <= 0.41421356f * ax) return 0;          // E/W
    if (ay >= 2.41421356f * ax) return 1;          // N/S
    return ((gx > 0.f) == (gy > 0.f)) ? 2 : 3;     // NE/SW : NW/SE
}

struct Smem {
    float S0[40 * P];            // G (gray, 40x40), later B (blur, 36x36)
    float S1[40 * P];            // H (hblur, 40x36), later M (mag, 34x36)
    unsigned char axis[32 * 33];
    unsigned int wsum[4];
};

__device__ unsigned int edge_pass(const float* __restrict__ img, int r0, int c0,
                                  Smem& s, int tid)
{
    const float w0 = 0.05448868f, w1 = 0.24420134f, w2 = 0.40261996f,
                w3 = 0.24420134f, w4 = 0.05448868f;
    const bool colInterior = (c0 >= 32 && c0 <= 960);

    // ---- Stage A: gray into G (rows r0-4.., cols c0-4..c0+35) ----
    if (colInterior) {
        for (int t = tid; t < 400; t += 256) {     // 40 rows x 10 float4-groups
            int i = t / 10, q = t % 10;
            int rr = refl(r0 - 4 + i);
            const float4* pch = (const float4*)(img + (size_t)rr * N + (c0 - 4 + 4 * q));
            float4 r = pch[0];
            float4 g = pch[N * N / 4];
            float4 b = pch[2 * (N * N / 4)];
            float4 gy4;
            gy4.x = 0.299f * r.x + 0.587f * g.x + 0.114f * b.x;
            gy4.y = 0.299f * r.y + 0.587f * g.y + 0.114f * b.y;
            gy4.z = 0.299f * r.z + 0.587f * g.z + 0.114f * b.z;
            gy4.w = 0.299f * r.w + 0.587f * g.w + 0.114f * b.w;
            *(float4*)&s.S0[i * P + 4 * q] = gy4;
        }
    } else {
        for (int t = tid; t < 1600; t += 256) {
            int i = t / 40, j = t % 40;
            int rr = refl(r0 - 4 + i);
            int cc = refl(c0 - 4 + j);
            size_t o = (size_t)rr * N + cc;
            s.S0[i * P + j] = 0.299f * img[o] + 0.587f * img[o + (size_t)N * N]
                            + 0.114f * img[o + 2 * (size_t)N * N];
        }
    }
    __syncthreads();

    // ---- Stage B-h: horizontal blur G->H ----
    for (int t = tid; t < 360; t += 256) {         // 40 rows x 9 groups
        int i = t / 9, q = t % 9;
        const float* gp = &s.S0[i * P + 4 * q];
        float4 g0 = *(const float4*)gp;
        float4 g1 = *(const float4*)(gp + 4);
        float4 h;
        h.x = w0 * g0.x + w1 * g0.y + w2 * g0.z + w3 * g0.w + w4 * g1.x;
        h.y = w0 * g0.y + w1 * g0.z + w2 * g0.w + w3 * g1.x + w4 * g1.y;
        h.z = w0 * g0.z + w1 * g0.w + w2 * g1.x + w3 * g1.y + w4 * g1.z;
        h.w = w0 * g0.w + w1 * g1.x + w2 * g1.y + w3 * g1.z + w4 * g1.w;
        *(float4*)&s.S1[i * P + 4 * q] = h;
    }
    __syncthreads();

    // ---- Stage B-v: vertical blur H->B ----
    for (int t = tid; t < 324; t += 256) {         // 36 rows x 9 groups
        int i = t / 9, q = t % 9;
        const float* hp = &s.S1[i * P + 4 * q];
        float4 h0 = *(const float4*)hp;
        float4 h1 = *(const float4*)(hp + P);
        float4 h2 = *(const float4*)(hp + 2 * P);
        float4 h3 = *(const float4*)(hp + 3 * P);
        float4 h4 = *(const float4*)(hp + 4 * P);
        float4 b;
        b.x = w0 * h0.x + w1 * h1.x + w2 * h2.x + w3 * h3.x + w4 * h4.x;
        b.y = w0 * h0.y + w1 * h1.y + w2 * h2.y + w3 * h3.y + w4 * h4.y;
        b.z = w0 * h0.z + w1 * h1.z + w2 * h2.z + w3 * h3.z + w4 * h4.z;
        b.w = w0 * h0.w + w1 * h1.w + w2 * h2.w + w3 * h3.w + w4 * h4.w;
        *(float4*)&s.S0[i * P + 4 * q] = b;
    }
    __syncthreads();

    // ---- Stage C: Sobel magnitude B->M (+axis for centers) ----
    if (colInterior) {
        for (int t = tid; t < 306; t += 256) {     // 34 rows x 9 groups
            int i = t / 9, q = t % 9;
            int gr = r0 - 1 + i;
            int rci = i + 1;
            int rmi = (gr - 1 < 0 ? 0 : gr - 1) - (r0 - 2);
            int rpi = (gr + 1 > N - 1 ? N - 1 : gr + 1) - (r0 - 2);
            const float* bp = &s.S0[4 * q];
            float4 t0 = *(const float4*)(bp + rmi * P);
            float4 t1 = *(const float4*)(bp + rmi * P + 4);
            float4 m0 = *(const float4*)(bp + rci * P);
            float4 m1 = *(const float4*)(bp + rci * P + 4);
            float4 b0 = *(const float4*)(bp + rpi * P);
            float4 b1 = *(const float4*)(bp + rpi * P + 4);
            float tr[6] = {t0.x, t0.y, t0.z, t0.w, t1.x, t1.y};
            float mr[6] = {m0.x, m0.y, m0.z, m0.w, m1.x, m1.y};
            float br[6] = {b0.x, b0.y, b0.z, b0.w, b1.x, b1.y};
            float4 mag;
            float mk[4];
#pragma unroll
            for (int k = 0; k < 4; ++k) {
                float gx = (tr[k + 2] - tr[k]) + 2.f * (mr[k + 2] - mr[k]) + (br[k + 2] - br[k]);
                float gyv = (br[k] - tr[k]) + 2.f * (br[k + 1] - tr[k + 1]) + (br[k + 2] - tr[k + 2]);
                mk[k] = sqrtf(gx * gx + gyv * gyv + 1e-6f);
                int jj = 4 * q + k;
                if (i >= 1 && i <= 32 && jj >= 1 && jj <= 32)
                    s.axis[(i - 1) * 33 + (jj - 1)] = (unsigned char)axis_code(gx, gyv);
            }
            mag.x = mk[0]; mag.y = mk[1]; mag.z = mk[2]; mag.w = mk[3];
            *(float4*)&s.S1[i * P + 4 * q] = mag;
        }
    } else {
        for (int p = tid; p < 34 * 34; p += 256) {
            int i = p / 34, j = p % 34;
            int gr = r0 - 1 + i, gc = c0 - 1 + j;
            float m = 0.f;
            if (gr >= 0 && gr < N && gc >= 0 && gc < N) {
                int rm = clampi(gr - 1) - (r0 - 2), rc = gr - (r0 - 2), rp = clampi(gr + 1) - (r0 - 2);
                int cm = clampi(gc - 1) - (c0 - 2), cc = gc - (c0 - 2), cp = clampi(gc + 1) - (c0 - 2);
                float a00 = s.S0[rm * P + cm], a01 = s.S0[rm * P + cc], a02 = s.S0[rm * P + cp];
                float a10 = s.S0[rc * P + cm],                          a12 = s.S0[rc * P + cp];
                float a20 = s.S0[rp * P + cm], a21 = s.S0[rp * P + cc], a22 = s.S0[rp * P + cp];
                float gx = (a02 - a00) + 2.f * (a12 - a10) + (a22 - a20);
                float gyv = (a20 - a00) + 2.f * (a21 - a01) + (a22 - a02);
                m = sqrtf(gx * gx + gyv * gyv + 1e-6f);
                if (i >= 1 && i <= 32 && j >= 1 && j <= 32)
                    s.axis[(i - 1) * 33 + (j - 1)] = (unsigned char)axis_code(gx, gyv);
            }
            s.S1[i * P + j] = m;
        }
    }
    __syncthreads();

    // ---- Stage D: NMS + threshold -> 4 edge bits per thread ----
    unsigned int bits = 0;
#pragma unroll
    for (int k = 0; k < 4; ++k) {
        int p = tid + 256 * k;
        int pr = p >> 5, pc = p & 31;
        float m = s.S1[(pr + 1) * P + (pc + 1)];
        int code = s.axis[pr * 33 + pc];
        int dr = (code == 0) ? 0 : -1;
        int dc = (code == 1) ? 0 : ((code == 3) ? -1 : 1);
        int gr = r0 + pr, gc = c0 + pc;
        int r1 = gr + dr, c1 = gc + dc;
        int r2 = gr - dr, c2 = gc - dc;
        float n1 = (r1 >= 0 && r1 < N && c1 >= 0 && c1 < N)
                     ? s.S1[(pr + 1 + dr) * P + (pc + 1 + dc)] : 0.f;
        float n2 = (r2 >= 0 && r2 < N && c2 >= 0 && c2 < N)
                     ? s.S1[(pr + 1 - dr) * P + (pc + 1 - dc)] : 0.f;
        bool edge = (m - n1 > 0.f) && (m - n2 > 0.f) && (m > 0.1f);
        bits |= (unsigned)edge << k;
    }
    return bits;
}

__global__ __launch_bounds__(256)
void edge_diff_kernel(const float* __restrict__ op, const float* __restrict__ gt,
                      unsigned int* __restrict__ partials)
{
    __shared__ Smem s;
    int tid = threadIdx.x;
    int b = blockIdx.z;
    int r0 = blockIdx.y * T, c0 = blockIdx.x * T;
    const float* imgA = op + (size_t)b * 3 * N * N;
    const float* imgB = gt + (size_t)b * 3 * N * N;

    unsigned int e1 = edge_pass(imgA, r0, c0, s, tid);
    __syncthreads();
    unsigned int e2 = edge_pass(imgB, r0, c0, s, tid);

    int d = __popc(e1 ^ e2);
    for (int off = 32; off > 0; off >>= 1)
        d += __shfl_down(d, off, 64);
    if ((tid & 63) == 0)
        s.wsum[tid >> 6] = (unsigned int)d;
    __syncthreads();
    if (tid == 0) {
        unsigned int tot = s.wsum[0] + s.wsum[1] + s.wsum[2] + s.wsum[3];
        int blk = (blockIdx.z * gridDim.y + blockIdx.y) * gridDim.x + blockIdx.x;
        partials[blk] = tot;   // plain store — no atomic, no contention
    }
}

__global__ __launch_bounds__(256)
void finalize_kernel(const unsigned int* __restrict__ partials, float* __restrict__ out)
{
    __shared__ unsigned int ws[4];
    int tid = threadIdx.x;
    unsigned int sum = 0;
    for (int i = tid; i < NBLK; i += 256)
        sum += partials[i];
    int d = (int)sum;
    for (int off = 32; off > 0; off >>= 1)
        d += __shfl_down(d, off, 64);
    if ((tid & 63) == 0) ws[tid >> 6] = (unsigned int)d;
    __syncthreads();
    if (tid == 0)
        out[0] = (float)(ws[0] + ws[1] + ws[2] + ws[3]) / 8388608.0f;  // 8*1024*1024
}

extern "C" void kernel_launch(void* const* d_in, const int* in_sizes, int n_in,
                              void* d_out, int out_size, void* d_ws, size_t ws_size,
                              hipStream_t stream)
{
    const float* op = (const float*)d_in[0];
    const float* gt = (const float*)d_in[1];
    unsigned int* partials = (unsigned int*)d_ws;   // NBLK uints, fully overwritten

    dim3 grid(N / T, N / T, 8);
    edge_diff_kernel<<<grid, dim3(256), 0, stream>>>(op, gt, partials);
    finalize_kernel<<<1, dim3(256), 0, stream>>>(partials, (float*)d_out);
}